// Round 5
// baseline (583.909 us; speedup 1.0000x reference)
//
#include <hip/hip_runtime.h>
#include <hip/hip_bf16.h>

// Problem dims (fixed): B=64, Te=1024, De=Dd=H=1024.
#define B_  64
#define TE  1024
#define K_  1024
#define HH  1024
#define MM  (B_ * TE)

typedef __bf16 bf16x8 __attribute__((ext_vector_type(8)));
typedef __bf16 bf16x4 __attribute__((ext_vector_type(4)));
typedef float  f32x4  __attribute__((ext_vector_type(4)));

__device__ __forceinline__ float fast_tanh(float x) {
    float ax = __builtin_fabsf(x);
    float t  = __expf(-2.0f * ax);
    float r  = (1.0f - t) * __builtin_amdgcn_rcpf(1.0f + t);
    return __builtin_copysignf(r, x);
}

// ---------------------------------------------------------------- Ua_w fp32 -> Bt bf16 (MFMA-frag order)
// Element B[h][k] stored at ((h>>4)*32 + (k>>5))*512 + ((k>>3)&3)*128 + (h&15)*8 + (k&7)
// so a wave's 16x32 B-fragment (one n-tile, one k-slab) is one contiguous 1 KB read.
__global__ void bt_kernel(const float* __restrict__ Uw, __bf16* __restrict__ Bt) {
    int i = blockIdx.x * 256 + threadIdx.x;     // 131072 threads; kc = i&127, h = i>>7
    int kc = i & 127, h = i >> 7;
    const float4* src = (const float4*)(Uw + (long)h * 1024 + kc * 8);
    float4 a = src[0], b = src[1];
    bf16x8 v;
    v[0] = (__bf16)a.x; v[1] = (__bf16)a.y; v[2] = (__bf16)a.z; v[3] = (__bf16)a.w;
    v[4] = (__bf16)b.x; v[5] = (__bf16)b.y; v[6] = (__bf16)b.z; v[7] = (__bf16)b.w;
    long dst = ((long)((h >> 4) * 32 + (kc >> 2)) * 512) + (kc & 3) * 128 + (h & 15) * 8;
    *(bf16x8*)(Bt + dst) = v;
}

// ---------------------------------------------------------------- Wa[b,h] = dec[b]·Wa_w[h] + Wa_b[h]
__global__ void wa_kernel(const float* __restrict__ dec, const float* __restrict__ Wa_w,
                          const float* __restrict__ Wa_b, float* __restrict__ WaOut) {
    int b = blockIdx.x, ht = blockIdx.y;
    int wave = threadIdx.x >> 6, lane = threadIdx.x & 63;
    const float* db = dec + b * 1024;
    for (int i = 0; i < 16; i++) {
        int h = ht * 64 + wave * 16 + i;
        const float* wr = Wa_w + (long)h * 1024;
        float a = 0.0f;
        #pragma unroll
        for (int k = 0; k < 16; k++)
            a += db[lane + 64 * k] * wr[lane + 64 * k];
        #pragma unroll
        for (int off = 32; off > 0; off >>= 1)
            a += __shfl_xor(a, off, 64);
        if (lane == 0) WaOut[b * 1024 + h] = a + Wa_b[h];
    }
}

// ---------------------------------------------------------------- fused score GEMM
// scores[m] += sum_h Va_w[h]*tanh(enc[m,:]·Ua_w[h,:] + Wa[b,h] + Ua_b[h])
// A: fp32 global -> reg prefetch -> cvt -> double-buffered LDS (8 KB slabs, KT=32).
// B: NO LDS — fragments read straight from L2 in Bt frag-order, 1-iter reg prefetch.
// Block 128 rows x 256 cols; 4 waves 2x2; wave tile 64x128; acc[4][8]=128 f32/lane.
#define MT 128
#define NP 256
#define KT 32
#define NIT (K_ / KT)

__global__ __launch_bounds__(256, 2) void score_gemm(
    const float* __restrict__ Af,    // [MM][1024] enc fp32
    __bf16* __restrict__ encB,       // [MM][1024] bf16 (written by y==0 blocks)
    const __bf16* __restrict__ Bt,   // Ua_w bf16, frag-order
    const float* __restrict__ Wa,    // [64][1024]
    const float* __restrict__ Ua_b,  // [1024]
    const float* __restrict__ Va_w,  // [1024]
    float* __restrict__ scores)      // [MM], pre-zeroed, atomic accumulate
{
    __shared__ __bf16 sA[2][MT * KT];   // 2 x 8 KB, swizzled: slot p holds seg p^((r>>1)&3)
    __shared__ float sVa[NP];
    __shared__ float sWU[NP];

    const int tid  = threadIdx.x;
    const int wave = tid >> 6;
    const int lane = tid & 63;
    const int quad = lane >> 4;
    const int l16  = lane & 15;
    const int wm   = wave >> 1;
    const int wn   = wave & 1;

    // bid -> (x strip, y quarter); groups of 32 bids = 8 XCD slots x 4 y sharing x.
    const int bid = blockIdx.x;
    const int grp = bid >> 5;
    const int r5  = bid & 31;
    const int y   = r5 >> 3;
    const int x   = grp * 8 + (r5 & 7);

    const int rowBase = x * MT;
    const int colBase = y * NP;
    const int b       = rowBase >> 10;
    const bool wb     = (y == 0);

    sVa[tid] = Va_w[colBase + tid];
    sWU[tid] = Wa[b * 1024 + colBase + tid] + Ua_b[colBase + tid];

    // A staging: 512 chunks of 8 bf16; thread owns c = tid, tid+256.
    int rA[2], sgA[2], cc[2];
    #pragma unroll
    for (int i = 0; i < 2; i++) {
        cc[i]  = i * 256 + tid;
        rA[i]  = cc[i] >> 2;
        sgA[i] = (cc[i] & 3) ^ ((rA[i] >> 1) & 3);
    }

    const long aBase = (long)rowBase * K_;
    const int  tb0   = (colBase >> 4) + wn * 8;   // first of my 8 B-tiles

    f32x4 acc[4][8] = {};

    // ---- preamble: stage slab 0
    {
        #pragma unroll
        for (int i = 0; i < 2; i++) {
            const float4* p = (const float4*)(Af + aBase + (long)rA[i] * K_ + sgA[i] * 8);
            float4 a = p[0], bq = p[1];
            bf16x8 v;
            v[0] = (__bf16)a.x;  v[1] = (__bf16)a.y;  v[2] = (__bf16)a.z;  v[3] = (__bf16)a.w;
            v[4] = (__bf16)bq.x; v[5] = (__bf16)bq.y; v[6] = (__bf16)bq.z; v[7] = (__bf16)bq.w;
            *(bf16x8*)(&sA[0][0] + cc[i] * 8) = v;
            if (wb) *(bf16x8*)(encB + aBase + (long)rA[i] * K_ + sgA[i] * 8) = v;
        }
    }
    __syncthreads();

    // ---- B frag prefetch for it=0
    bf16x8 bcur[8];
    #pragma unroll
    for (int t = 0; t < 8; t++)
        bcur[t] = *(const bf16x8*)(Bt + ((long)(tb0 + t) * 32 + 0) * 512 + lane * 8);

    #pragma unroll 2
    for (int it = 0; it < NIT; it++) {
        const int cur = it & 1;

        // prefetch next A slab (fp32) and next B frags — land during MFMA phase
        float4 pn[2][2];
        bf16x8 bnext[8];
        if (it < NIT - 1) {
            #pragma unroll
            for (int i = 0; i < 2; i++) {
                const float4* p = (const float4*)(Af + aBase + (long)rA[i] * K_ + (it + 1) * KT + sgA[i] * 8);
                pn[i][0] = p[0]; pn[i][1] = p[1];
            }
            #pragma unroll
            for (int t = 0; t < 8; t++)
                bnext[t] = *(const bf16x8*)(Bt + ((long)(tb0 + t) * 32 + (it + 1)) * 512 + lane * 8);
        }

        // compute on sA[cur] + bcur
        #pragma unroll
        for (int s = 0; s < 4; s++) {
            int r  = wm * 64 + s * 16 + l16;
            int ps = quad ^ ((r >> 1) & 3);
            bf16x8 af = *(const bf16x8*)(&sA[cur][0] + r * KT + ps * 8);
            #pragma unroll
            for (int t = 0; t < 8; t++)
                acc[s][t] = __builtin_amdgcn_mfma_f32_16x16x32_bf16(af, bcur[t], acc[s][t], 0, 0, 0);
        }

        // stage next slab into the other buffer
        if (it < NIT - 1) {
            #pragma unroll
            for (int i = 0; i < 2; i++) {
                bf16x8 v;
                v[0] = (__bf16)pn[i][0].x; v[1] = (__bf16)pn[i][0].y;
                v[2] = (__bf16)pn[i][0].z; v[3] = (__bf16)pn[i][0].w;
                v[4] = (__bf16)pn[i][1].x; v[5] = (__bf16)pn[i][1].y;
                v[6] = (__bf16)pn[i][1].z; v[7] = (__bf16)pn[i][1].w;
                *(bf16x8*)(&sA[1 - cur][0] + cc[i] * 8) = v;
                if (wb) *(bf16x8*)(encB + aBase + (long)rA[i] * K_ + (it + 1) * KT + sgA[i] * 8) = v;
            }
            #pragma unroll
            for (int t = 0; t < 8; t++) bcur[t] = bnext[t];
        }
        __syncthreads();   // readers of sA[cur] done; writers of sA[1-cur] done
    }

    // Epilogue. C/D layout: row = quad*4 + reg, col = l16.
    float rs[4][4] = {};
    #pragma unroll
    for (int s = 0; s < 4; s++)
        #pragma unroll
        for (int t = 0; t < 8; t++) {
            int hl = wn * 128 + t * 16 + l16;
            float va = sVa[hl], wu = sWU[hl];
            #pragma unroll
            for (int r = 0; r < 4; r++)
                rs[s][r] += va * fast_tanh(acc[s][t][r] + wu);
        }

    #pragma unroll
    for (int s = 0; s < 4; s++)
        #pragma unroll
        for (int r = 0; r < 4; r++) {
            float v = rs[s][r];
            v += __shfl_xor(v, 1, 64);
            v += __shfl_xor(v, 2, 64);
            v += __shfl_xor(v, 4, 64);
            v += __shfl_xor(v, 8, 64);
            if (l16 == 0)
                atomicAdd(&scores[rowBase + wm * 64 + s * 16 + quad * 4 + r], v);
        }
}

// ---------------------------------------------------------------- softmax over Te, in place
__global__ void softmax_kernel(float* __restrict__ s) {
    __shared__ float red[256];
    int b = blockIdx.x, tid = threadIdx.x;
    float4* row = (float4*)(s + b * 1024);
    float4 v = row[tid];
    float m = fmaxf(fmaxf(v.x, v.y), fmaxf(v.z, v.w));
    red[tid] = m; __syncthreads();
    for (int off = 128; off > 0; off >>= 1) {
        if (tid < off) red[tid] = fmaxf(red[tid], red[tid + off]);
        __syncthreads();
    }
    m = red[0]; __syncthreads();
    v.x = expf(v.x - m); v.y = expf(v.y - m); v.z = expf(v.z - m); v.w = expf(v.w - m);
    red[tid] = v.x + v.y + v.z + v.w; __syncthreads();
    for (int off = 128; off > 0; off >>= 1) {
        if (tid < off) red[tid] += red[tid + off];
        __syncthreads();
    }
    float inv = 1.0f / red[0];
    v.x *= inv; v.y *= inv; v.z *= inv; v.w *= inv;
    row[tid] = v;
}

// ---------------------------------------------------------------- context from bf16 enc
__global__ void context_kernel(const __bf16* __restrict__ enc, const float* __restrict__ w,
                               float* __restrict__ out) {
    int b = blockIdx.x, ec = blockIdx.y, tid = threadIdx.x;
    const bf16x4* enc4 = (const bf16x4*)(enc + ((long)b * 1024 + ec * 64) * 1024);
    const float* wrow = w + b * 1024 + ec * 64;
    float ax = 0, ay = 0, az = 0, aw = 0;
    for (int e = 0; e < 64; e++) {
        float we = wrow[e];
        bf16x4 v = enc4[e * 256 + tid];
        ax += we * (float)v[0]; ay += we * (float)v[1];
        az += we * (float)v[2]; aw += we * (float)v[3];
    }
    float* o = out + b * 1024 + tid * 4;
    atomicAdd(o + 0, ax); atomicAdd(o + 1, ay);
    atomicAdd(o + 2, az); atomicAdd(o + 3, aw);
}

// ----------------------------------------------------------------
extern "C" void kernel_launch(void* const* d_in, const int* in_sizes, int n_in,
                              void* d_out, int out_size, void* d_ws, size_t ws_size,
                              hipStream_t stream) {
    (void)in_sizes; (void)n_in; (void)ws_size;
    const float* enc   = (const float*)d_in[0];
    const float* dec   = (const float*)d_in[1];
    const float* Wa_w  = (const float*)d_in[2];
    const float* Wa_b  = (const float*)d_in[3];
    const float* Ua_w  = (const float*)d_in[4];
    const float* Ua_b  = (const float*)d_in[5];
    const float* Va_w  = (const float*)d_in[6];
    // d_in[7] = Va_b: softmax-invariant -> dropped.
    float* out = (float*)d_out;

    char* w = (char*)d_ws;
    __bf16* encB = (__bf16*)w;  w += (size_t)MM * 1024 * 2;
    __bf16* BtB  = (__bf16*)w;  w += (size_t)HH * 1024 * 2;
    float* WaBuf = (float*)w;   w += (size_t)B_ * HH * 4;
    float* scores = (float*)w;  w += (size_t)MM * 4;

    hipMemsetAsync(scores, 0, (size_t)MM * 4, stream);
    hipMemsetAsync(out, 0, (size_t)out_size * 4, stream);
    bt_kernel<<<dim3(512), 256, 0, stream>>>(Ua_w, BtB);
    wa_kernel<<<dim3(B_, 16), 256, 0, stream>>>(dec, Wa_w, Wa_b, WaBuf);
    score_gemm<<<dim3((MM / MT) * (HH / NP)), 256, 0, stream>>>(enc, encB, BtB, WaBuf, Ua_b, Va_w, scores);
    softmax_kernel<<<dim3(B_), 256, 0, stream>>>(scores);
    context_kernel<<<dim3(B_, 16), 256, 0, stream>>>(encB, scores, out);
}